// Round 1
// baseline (2798.611 us; speedup 1.0000x reference)
//
#include <hip/hip_runtime.h>

#define HID 128
#define INP 64
#define LN_EPS 1e-5f

// ---------------- CSR build ----------------
__global__ void k_count(const int* __restrict__ dst, int nE, int* __restrict__ cnt) {
    int e = blockIdx.x * blockDim.x + threadIdx.x;
    if (e < nE) atomicAdd(&cnt[dst[e]], 1);
}

// per-block exclusive scan of 256 elems; partial (no block offset) -> rowp, block totals -> bsum
__global__ void k_scan1(const int* __restrict__ cnt, int n, int* __restrict__ rowp, int* __restrict__ bsum) {
    __shared__ int s[256];
    int i = blockIdx.x * 256 + threadIdx.x;
    int v = (i < n) ? cnt[i] : 0;
    s[threadIdx.x] = v;
    __syncthreads();
    for (int off = 1; off < 256; off <<= 1) {
        int t = (threadIdx.x >= off) ? s[threadIdx.x - off] : 0;
        __syncthreads();
        s[threadIdx.x] += t;
        __syncthreads();
    }
    if (i < n) rowp[i] = s[threadIdx.x] - v;  // exclusive
    if (threadIdx.x == 255) bsum[blockIdx.x] = s[255];
}

// single-block exclusive scan of block sums (nb <= 256)
__global__ void k_scan2(int* __restrict__ bsum, int nb) {
    __shared__ int s[256];
    int v = (threadIdx.x < nb) ? bsum[threadIdx.x] : 0;
    s[threadIdx.x] = v;
    __syncthreads();
    for (int off = 1; off < 256; off <<= 1) {
        int t = (threadIdx.x >= off) ? s[threadIdx.x - off] : 0;
        __syncthreads();
        s[threadIdx.x] += t;
        __syncthreads();
    }
    if (threadIdx.x < nb) bsum[threadIdx.x] = s[threadIdx.x] - v;
}

__global__ void k_scan3(int* __restrict__ rowp, const int* __restrict__ bsum, const int* __restrict__ cnt,
                        int n, int nE, int* __restrict__ cursor, float* __restrict__ invd) {
    int i = blockIdx.x * 256 + threadIdx.x;
    if (i < n) {
        int rp = rowp[i] + bsum[blockIdx.x];
        rowp[i] = rp;
        cursor[i] = rp;
        int c = cnt[i];
        invd[i] = 1.0f / (float)(c > 1 ? c : 1);
    } else if (i == n) {
        rowp[n] = nE;
    }
}

__global__ void k_fill(const int* __restrict__ src, const int* __restrict__ dst, int nE,
                       int* __restrict__ cursor, int* __restrict__ csrc) {
    int e = blockIdx.x * blockDim.x + threadIdx.x;
    if (e < nE) {
        int p = atomicAdd(&cursor[dst[e]], 1);
        csrc[p] = src[e];
    }
}

// ---------------- aggregation: agg[v] = (sum_{u in N(v)} h[u]) * invd[v] ----------------
__global__ __launch_bounds__(256) void k_agg(const float* __restrict__ h, const int* __restrict__ rowp,
                                             const int* __restrict__ csrc, const float* __restrict__ invd,
                                             float* __restrict__ agg, int n) {
    int node = blockIdx.x * 2 + (threadIdx.x >> 7);
    int c = threadIdx.x & 127;
    if (node >= n) return;
    int e0 = rowp[node], e1 = rowp[node + 1];
    float acc = 0.f;
    for (int e = e0; e < e1; ++e) {
        int s = csrc[e];
        acc += h[(size_t)s * HID + c];
    }
    agg[(size_t)node * HID + c] = acc * invd[node];
}

// ---------------- in-projection: h = x @ W_in + b_in ----------------
__global__ __launch_bounds__(256) void k_inproj(const float* __restrict__ x, const float* __restrict__ W,
                                                const float* __restrict__ b, float* __restrict__ h, int n) {
    __shared__ float xl[32 * INP];
    const int tid = threadIdx.x;
    const int row0 = blockIdx.x * 32;
    {
        int r = tid >> 3, c = (tid & 7) * 8;
        int grow = row0 + r;
        float4* op = reinterpret_cast<float4*>(xl + r * INP + c);
        if (grow < n) {
            const float4* xp = reinterpret_cast<const float4*>(x + (size_t)grow * INP + c);
            op[0] = xp[0];
            op[1] = xp[1];
        } else {
            float4 z = {0, 0, 0, 0};
            op[0] = z; op[1] = z;
        }
    }
    __syncthreads();
    const int cg = tid & 31, rg = tid >> 5, c2 = cg * 4;
    float acc[4][4];
    float4 bb = *reinterpret_cast<const float4*>(b + c2);
#pragma unroll
    for (int rr = 0; rr < 4; ++rr) { acc[rr][0] = bb.x; acc[rr][1] = bb.y; acc[rr][2] = bb.z; acc[rr][3] = bb.w; }

    for (int k = 0; k < INP; k += 4) {
        float4 a[4];
#pragma unroll
        for (int rr = 0; rr < 4; ++rr)
            a[rr] = *reinterpret_cast<const float4*>(xl + (rg + 8 * rr) * INP + k);
#pragma unroll
        for (int j = 0; j < 4; ++j) {
            float4 w = *reinterpret_cast<const float4*>(W + (size_t)(k + j) * HID + c2);
#pragma unroll
            for (int rr = 0; rr < 4; ++rr) {
                float av = (j == 0) ? a[rr].x : (j == 1) ? a[rr].y : (j == 2) ? a[rr].z : a[rr].w;
                acc[rr][0] += av * w.x; acc[rr][1] += av * w.y;
                acc[rr][2] += av * w.z; acc[rr][3] += av * w.w;
            }
        }
    }
#pragma unroll
    for (int rr = 0; rr < 4; ++rr) {
        int grow = row0 + rg + 8 * rr;
        if (grow < n) {
            float4 ov = {acc[rr][0], acc[rr][1], acc[rr][2], acc[rr][3]};
            *reinterpret_cast<float4*>(h + (size_t)grow * HID + c2) = ov;
        }
    }
}

// ---------------- fused layer: h = relu(LN((h+agg)@W + b)*g + lnb) + h, in place ----------------
__global__ __launch_bounds__(256) void k_layer(float* __restrict__ h, const float* __restrict__ agg,
                                               const float* __restrict__ W, const float* __restrict__ bias,
                                               const float* __restrict__ g, const float* __restrict__ lnb, int n) {
    __shared__ float in_lds[32 * HID];
    const int tid = threadIdx.x;
    const int row0 = blockIdx.x * 32;
    // stage (h+agg) tile
    {
        int r = tid >> 3, c = (tid & 7) * 16;
        int grow = row0 + r;
        float4* op = reinterpret_cast<float4*>(in_lds + r * HID + c);
        if (grow < n) {
            const float4* hp = reinterpret_cast<const float4*>(h + (size_t)grow * HID + c);
            const float4* ap = reinterpret_cast<const float4*>(agg + (size_t)grow * HID + c);
#pragma unroll
            for (int j = 0; j < 4; ++j) {
                float4 a = hp[j], b2 = ap[j];
                float4 o;
                o.x = a.x + b2.x; o.y = a.y + b2.y; o.z = a.z + b2.z; o.w = a.w + b2.w;
                op[j] = o;
            }
        } else {
            float4 z = {0, 0, 0, 0};
#pragma unroll
            for (int j = 0; j < 4; ++j) op[j] = z;
        }
    }
    __syncthreads();

    const int cg = tid & 31, rg = tid >> 5, c2 = cg * 4;
    float acc[4][4];
    float4 bb = *reinterpret_cast<const float4*>(bias + c2);
#pragma unroll
    for (int rr = 0; rr < 4; ++rr) { acc[rr][0] = bb.x; acc[rr][1] = bb.y; acc[rr][2] = bb.z; acc[rr][3] = bb.w; }

    for (int k = 0; k < HID; k += 4) {
        float4 a[4];
#pragma unroll
        for (int rr = 0; rr < 4; ++rr)
            a[rr] = *reinterpret_cast<const float4*>(in_lds + (rg + 8 * rr) * HID + k);
#pragma unroll
        for (int j = 0; j < 4; ++j) {
            float4 w = *reinterpret_cast<const float4*>(W + (size_t)(k + j) * HID + c2);
#pragma unroll
            for (int rr = 0; rr < 4; ++rr) {
                float av = (j == 0) ? a[rr].x : (j == 1) ? a[rr].y : (j == 2) ? a[rr].z : a[rr].w;
                acc[rr][0] += av * w.x; acc[rr][1] += av * w.y;
                acc[rr][2] += av * w.z; acc[rr][3] += av * w.w;
            }
        }
    }

    float4 gv = *reinterpret_cast<const float4*>(g + c2);
    float4 lb = *reinterpret_cast<const float4*>(lnb + c2);
#pragma unroll
    for (int rr = 0; rr < 4; ++rr) {
        int grow = row0 + rg + 8 * rr;
        float s = acc[rr][0] + acc[rr][1] + acc[rr][2] + acc[rr][3];
        float q = acc[rr][0] * acc[rr][0] + acc[rr][1] * acc[rr][1] +
                  acc[rr][2] * acc[rr][2] + acc[rr][3] * acc[rr][3];
#pragma unroll
        for (int m = 1; m < 32; m <<= 1) {
            s += __shfl_xor(s, m, 64);
            q += __shfl_xor(q, m, 64);
        }
        float mu = s * (1.0f / HID);
        float var = q * (1.0f / HID) - mu * mu;
        float rs = rsqrtf(var + LN_EPS);
        if (grow < n) {
            const float4 res = *reinterpret_cast<const float4*>(h + (size_t)grow * HID + c2);
            float o0 = fmaxf((acc[rr][0] - mu) * rs * gv.x + lb.x, 0.f) + res.x;
            float o1 = fmaxf((acc[rr][1] - mu) * rs * gv.y + lb.y, 0.f) + res.y;
            float o2 = fmaxf((acc[rr][2] - mu) * rs * gv.z + lb.z, 0.f) + res.z;
            float o3 = fmaxf((acc[rr][3] - mu) * rs * gv.w + lb.w, 0.f) + res.w;
            float4 ov = {o0, o1, o2, o3};
            *reinterpret_cast<float4*>(h + (size_t)grow * HID + c2) = ov;
        }
    }
}

// ---------------- final: accum[c] = sum over rows < n_act of h[r][c] ----------------
__global__ void k_rowsum(const float* __restrict__ h, const int* __restrict__ n_act_p,
                         float* __restrict__ accum, int n) {
    int na = *n_act_p;
    int row0 = blockIdx.x * 128;
    int c = threadIdx.x;
    int rend = row0 + 128;
    if (rend > na) rend = na;
    float s = 0.f;
    for (int r = row0; r < rend; ++r) s += h[(size_t)r * HID + c];
    if (row0 < na) atomicAdd(&accum[c], s);
}

// out = (accum/na) @ W_out + b_out
__global__ void k_out(const float* __restrict__ accum, const int* __restrict__ n_act_p,
                      const float* __restrict__ W_out, const float* __restrict__ b_out,
                      float* __restrict__ out) {
    __shared__ float m[HID];
    int c = threadIdx.x;
    float na = (float)(*n_act_p);
    m[c] = accum[c] / na;
    __syncthreads();
    float s = b_out[c];
    for (int k = 0; k < HID; ++k) s += m[k] * W_out[k * HID + c];
    out[c] = s;
}

extern "C" void kernel_launch(void* const* d_in, const int* in_sizes, int n_in,
                              void* d_out, int out_size, void* d_ws, size_t ws_size,
                              hipStream_t stream) {
    const int n  = in_sizes[0] / INP;   // 50000
    const int nE = in_sizes[1] / 2;     // 800000
    const float* x    = (const float*)d_in[0];
    const int*   ei   = (const int*)d_in[1];
    const int*   src  = ei;
    const int*   dst  = ei + nE;
    const int*   nact = (const int*)d_in[2];
    const float* W_in = (const float*)d_in[3];
    const float* b_in = (const float*)d_in[4];
    const float* W_l  = (const float*)d_in[5];
    const float* b_l  = (const float*)d_in[6];
    const float* lng  = (const float*)d_in[7];
    const float* lnb  = (const float*)d_in[8];
    const float* W_o  = (const float*)d_in[9];
    const float* b_o  = (const float*)d_in[10];

    char* ws = (char*)d_ws;
    size_t off = 0;
    auto alloc = [&](size_t bytes) {
        void* p = ws + off;
        off = (off + bytes + 255) & ~((size_t)255);
        return p;
    };
    float* h    = (float*)alloc((size_t)n * HID * 4);
    float* agg  = (float*)alloc((size_t)n * HID * 4);
    int*   cnt  = (int*)alloc((size_t)n * 4);
    int*   rowp = (int*)alloc((size_t)(n + 1) * 4);
    int*   curs = (int*)alloc((size_t)n * 4);
    float* invd = (float*)alloc((size_t)n * 4);
    int*   csrc = (int*)alloc((size_t)nE * 4);
    int*   bsum = (int*)alloc(1024);
    float* accum = (float*)alloc(HID * 4);

    hipMemsetAsync(cnt, 0, (size_t)n * 4, stream);
    hipMemsetAsync(accum, 0, HID * 4, stream);

    int egrid = (nE + 255) / 256;
    int nb = (n + 255) / 256;
    k_count<<<egrid, 256, 0, stream>>>(dst, nE, cnt);
    k_scan1<<<nb, 256, 0, stream>>>(cnt, n, rowp, bsum);
    k_scan2<<<1, 256, 0, stream>>>(bsum, nb);
    k_scan3<<<nb, 256, 0, stream>>>(rowp, bsum, cnt, n, nE, curs, invd);
    k_fill<<<egrid, 256, 0, stream>>>(src, dst, nE, curs, csrc);

    int tgrid = (n + 31) / 32;
    k_inproj<<<tgrid, 256, 0, stream>>>(x, W_in, b_in, h, n);
    for (int l = 0; l < 3; ++l) {
        k_agg<<<(n + 1) / 2, 256, 0, stream>>>(h, rowp, csrc, invd, agg, n);
        k_layer<<<tgrid, 256, 0, stream>>>(h, agg, W_l + (size_t)l * HID * HID,
                                           b_l + l * HID, lng + l * HID, lnb + l * HID, n);
    }
    k_rowsum<<<(n + 127) / 128, 128, 0, stream>>>(h, nact, accum, n);
    k_out<<<1, HID, 0, stream>>>(accum, nact, W_o, b_o, (float*)d_out);
}

// Round 2
// 509.955 us; speedup vs baseline: 5.4880x; 5.4880x over previous
//
#include <hip/hip_runtime.h>

#define HID 128
#define INP 64
#define LN_EPS 1e-5f
#define RT 64   // rows per block in GEMM kernels

// ---------------- CSR build ----------------
__global__ void k_count(const int* __restrict__ dst, int nE, int* __restrict__ cnt) {
    int e = blockIdx.x * blockDim.x + threadIdx.x;
    if (e < nE) atomicAdd(&cnt[dst[e]], 1);
}

__global__ void k_scan1(const int* __restrict__ cnt, int n, int* __restrict__ rowp, int* __restrict__ bsum) {
    __shared__ int s[256];
    int i = blockIdx.x * 256 + threadIdx.x;
    int v = (i < n) ? cnt[i] : 0;
    s[threadIdx.x] = v;
    __syncthreads();
    for (int off = 1; off < 256; off <<= 1) {
        int t = (threadIdx.x >= off) ? s[threadIdx.x - off] : 0;
        __syncthreads();
        s[threadIdx.x] += t;
        __syncthreads();
    }
    if (i < n) rowp[i] = s[threadIdx.x] - v;  // exclusive
    if (threadIdx.x == 255) bsum[blockIdx.x] = s[255];
}

__global__ void k_scan2(int* __restrict__ bsum, int nb) {
    __shared__ int s[256];
    int v = (threadIdx.x < nb) ? bsum[threadIdx.x] : 0;
    s[threadIdx.x] = v;
    __syncthreads();
    for (int off = 1; off < 256; off <<= 1) {
        int t = (threadIdx.x >= off) ? s[threadIdx.x - off] : 0;
        __syncthreads();
        s[threadIdx.x] += t;
        __syncthreads();
    }
    if (threadIdx.x < nb) bsum[threadIdx.x] = s[threadIdx.x] - v;
}

__global__ void k_scan3(int* __restrict__ rowp, const int* __restrict__ bsum, const int* __restrict__ cnt,
                        int n, int nE, int* __restrict__ cursor, float* __restrict__ invd) {
    int i = blockIdx.x * 256 + threadIdx.x;
    if (i < n) {
        int rp = rowp[i] + bsum[blockIdx.x];
        rowp[i] = rp;
        cursor[i] = rp;
        int c = cnt[i];
        invd[i] = 1.0f / (float)(c > 1 ? c : 1);
    } else if (i == n) {
        rowp[n] = nE;
    }
}

__global__ void k_fill(const int* __restrict__ src, const int* __restrict__ dst, int nE,
                       int* __restrict__ cursor, int* __restrict__ csrc) {
    int e = blockIdx.x * blockDim.x + threadIdx.x;
    if (e < nE) {
        int p = atomicAdd(&cursor[dst[e]], 1);
        csrc[p] = src[e];
    }
}

// ---------------- aggregation: agg[v] = (sum_{u in N(v)} h[u]) * invd[v] ----------------
// one wave per node, float2 per lane, 2-edge unroll for outstanding-load ILP
__global__ __launch_bounds__(256) void k_agg(const float* __restrict__ h, const int* __restrict__ rowp,
                                             const int* __restrict__ csrc, const float* __restrict__ invd,
                                             float* __restrict__ agg, int n) {
    int node = blockIdx.x * 4 + (threadIdx.x >> 6);
    if (node >= n) return;
    int lane = threadIdx.x & 63;
    int e0 = rowp[node], e1 = rowp[node + 1];
    const float2* __restrict__ h2 = reinterpret_cast<const float2*>(h);
    float ax = 0.f, ay = 0.f;
    int e = e0;
    for (; e + 2 <= e1; e += 2) {
        int s0 = csrc[e], s1 = csrc[e + 1];
        float2 v0 = h2[(size_t)s0 * 64 + lane];
        float2 v1 = h2[(size_t)s1 * 64 + lane];
        ax += v0.x + v1.x;
        ay += v0.y + v1.y;
    }
    if (e < e1) {
        int s0 = csrc[e];
        float2 v0 = h2[(size_t)s0 * 64 + lane];
        ax += v0.x;
        ay += v0.y;
    }
    float inv = invd[node];
    float2 o = {ax * inv, ay * inv};
    reinterpret_cast<float2*>(agg)[(size_t)node * 64 + lane] = o;
}

// ---------------- in-projection: h = x @ W_in + b_in ----------------
// 64 rows/block; x tile (16KB) + full W_in (32KB) in LDS; 8x4 outputs/thread
__global__ __launch_bounds__(256) void k_inproj(const float* __restrict__ x, const float* __restrict__ W,
                                                const float* __restrict__ b, float* __restrict__ h, int n) {
    __shared__ float xl[RT * INP];      // 16 KB
    __shared__ float wl[INP * HID];     // 32 KB
    const int tid = threadIdx.x;
    const int row0 = blockIdx.x * RT;

    // stage x tile: 64*64 floats = 1024 float4, 4/thread
#pragma unroll
    for (int j = 0; j < 4; ++j) {
        int fid = tid + j * 256;
        int r = fid >> 4, c = (fid & 15) * 4;    // 16 float4 per row of 64
        int grow = row0 + r;
        float4 v = {0, 0, 0, 0};
        if (grow < n) v = *reinterpret_cast<const float4*>(x + (size_t)grow * INP + c);
        *reinterpret_cast<float4*>(xl + r * INP + c) = v;
    }
    // stage W_in: 64*128 floats = 2048 float4, 8/thread
#pragma unroll
    for (int j = 0; j < 8; ++j) {
        int fid = tid + j * 256;
        int r = fid >> 5, c = (fid & 31) * 4;
        *reinterpret_cast<float4*>(wl + r * HID + c) = *reinterpret_cast<const float4*>(W + (size_t)r * HID + c);
    }
    __syncthreads();

    const int cg = tid & 31, rg = tid >> 5, c2 = cg * 4;
    float acc[8][4];
    float4 bb = *reinterpret_cast<const float4*>(b + c2);
#pragma unroll
    for (int rr = 0; rr < 8; ++rr) { acc[rr][0] = bb.x; acc[rr][1] = bb.y; acc[rr][2] = bb.z; acc[rr][3] = bb.w; }

#pragma unroll 1
    for (int kk = 0; kk < INP; kk += 4) {
        float4 a4[8];
#pragma unroll
        for (int rr = 0; rr < 8; ++rr)
            a4[rr] = *reinterpret_cast<const float4*>(xl + (rg * 8 + rr) * INP + kk);
#pragma unroll
        for (int j = 0; j < 4; ++j) {
            float4 w = *reinterpret_cast<const float4*>(wl + (kk + j) * HID + c2);
#pragma unroll
            for (int rr = 0; rr < 8; ++rr) {
                float av = (j == 0) ? a4[rr].x : (j == 1) ? a4[rr].y : (j == 2) ? a4[rr].z : a4[rr].w;
                acc[rr][0] += av * w.x; acc[rr][1] += av * w.y;
                acc[rr][2] += av * w.z; acc[rr][3] += av * w.w;
            }
        }
    }
#pragma unroll
    for (int rr = 0; rr < 8; ++rr) {
        int grow = row0 + rg * 8 + rr;
        if (grow < n) {
            float4 ov = {acc[rr][0], acc[rr][1], acc[rr][2], acc[rr][3]};
            *reinterpret_cast<float4*>(h + (size_t)grow * HID + c2) = ov;
        }
    }
}

// ---------------- fused layer: h = relu(LN((h+agg)@W + b)*g + lnb) + h, in place ----------------
// 64 rows/block; (h+agg) tile 32KB + W chunk 16KB in LDS; 8x4 outputs/thread
__global__ __launch_bounds__(256) void k_layer(float* __restrict__ h, const float* __restrict__ agg,
                                               const float* __restrict__ W, const float* __restrict__ bias,
                                               const float* __restrict__ g, const float* __restrict__ lnb, int n) {
    __shared__ float in_lds[RT * HID];  // 32 KB
    __shared__ float w_lds[32 * HID];   // 16 KB
    const int tid = threadIdx.x;
    const int row0 = blockIdx.x * RT;

    // stage (h+agg): 64*128 = 2048 float4, 8/thread
#pragma unroll
    for (int j = 0; j < 8; ++j) {
        int fid = tid + j * 256;
        int r = fid >> 5, c = (fid & 31) * 4;
        int grow = row0 + r;
        float4 v = {0, 0, 0, 0};
        if (grow < n) {
            float4 a = *reinterpret_cast<const float4*>(h + (size_t)grow * HID + c);
            float4 b2 = *reinterpret_cast<const float4*>(agg + (size_t)grow * HID + c);
            v.x = a.x + b2.x; v.y = a.y + b2.y; v.z = a.z + b2.z; v.w = a.w + b2.w;
        }
        *reinterpret_cast<float4*>(in_lds + r * HID + c) = v;
    }

    const int cg = tid & 31, rg = tid >> 5, c2 = cg * 4;
    float acc[8][4];
    float4 bb = *reinterpret_cast<const float4*>(bias + c2);
#pragma unroll
    for (int rr = 0; rr < 8; ++rr) { acc[rr][0] = bb.x; acc[rr][1] = bb.y; acc[rr][2] = bb.z; acc[rr][3] = bb.w; }

#pragma unroll 1
    for (int kc = 0; kc < HID; kc += 32) {
        __syncthreads();   // protect w_lds readers of previous chunk (covers in_lds staging at kc=0)
        // stage W[kc..kc+32): 32*128 = 1024 float4, 4/thread
#pragma unroll
        for (int j = 0; j < 4; ++j) {
            int fid = tid + j * 256;
            int wr = fid >> 5, wc = (fid & 31) * 4;
            *reinterpret_cast<float4*>(w_lds + wr * HID + wc) =
                *reinterpret_cast<const float4*>(W + (size_t)(kc + wr) * HID + wc);
        }
        __syncthreads();
#pragma unroll 1
        for (int kk = 0; kk < 32; kk += 4) {
            float4 a4[8];
#pragma unroll
            for (int rr = 0; rr < 8; ++rr)
                a4[rr] = *reinterpret_cast<const float4*>(in_lds + (rg * 8 + rr) * HID + kc + kk);
#pragma unroll
            for (int j = 0; j < 4; ++j) {
                float4 w = *reinterpret_cast<const float4*>(w_lds + (kk + j) * HID + c2);
#pragma unroll
                for (int rr = 0; rr < 8; ++rr) {
                    float av = (j == 0) ? a4[rr].x : (j == 1) ? a4[rr].y : (j == 2) ? a4[rr].z : a4[rr].w;
                    acc[rr][0] += av * w.x; acc[rr][1] += av * w.y;
                    acc[rr][2] += av * w.z; acc[rr][3] += av * w.w;
                }
            }
        }
    }

    float4 gv = *reinterpret_cast<const float4*>(g + c2);
    float4 lb = *reinterpret_cast<const float4*>(lnb + c2);
#pragma unroll
    for (int rr = 0; rr < 8; ++rr) {
        int grow = row0 + rg * 8 + rr;
        float s = acc[rr][0] + acc[rr][1] + acc[rr][2] + acc[rr][3];
        float q = acc[rr][0] * acc[rr][0] + acc[rr][1] * acc[rr][1] +
                  acc[rr][2] * acc[rr][2] + acc[rr][3] * acc[rr][3];
#pragma unroll
        for (int m = 1; m < 32; m <<= 1) {
            s += __shfl_xor(s, m, 64);
            q += __shfl_xor(q, m, 64);
        }
        float mu = s * (1.0f / HID);
        float var = q * (1.0f / HID) - mu * mu;
        float rs = rsqrtf(var + LN_EPS);
        if (grow < n) {
            const float4 res = *reinterpret_cast<const float4*>(h + (size_t)grow * HID + c2);
            float o0 = fmaxf((acc[rr][0] - mu) * rs * gv.x + lb.x, 0.f) + res.x;
            float o1 = fmaxf((acc[rr][1] - mu) * rs * gv.y + lb.y, 0.f) + res.y;
            float o2 = fmaxf((acc[rr][2] - mu) * rs * gv.z + lb.z, 0.f) + res.z;
            float o3 = fmaxf((acc[rr][3] - mu) * rs * gv.w + lb.w, 0.f) + res.w;
            float4 ov = {o0, o1, o2, o3};
            *reinterpret_cast<float4*>(h + (size_t)grow * HID + c2) = ov;
        }
    }
}

// ---------------- final: accum[c] = sum over rows < n_act of h[r][c] ----------------
__global__ void k_rowsum(const float* __restrict__ h, const int* __restrict__ n_act_p,
                         float* __restrict__ accum, int n) {
    int na = *n_act_p;
    int row0 = blockIdx.x * 128;
    int c = threadIdx.x;
    int rend = row0 + 128;
    if (rend > na) rend = na;
    float s = 0.f;
    for (int r = row0; r < rend; ++r) s += h[(size_t)r * HID + c];
    if (row0 < na) atomicAdd(&accum[c], s);
}

__global__ void k_out(const float* __restrict__ accum, const int* __restrict__ n_act_p,
                      const float* __restrict__ W_out, const float* __restrict__ b_out,
                      float* __restrict__ out) {
    __shared__ float m[HID];
    int c = threadIdx.x;
    float na = (float)(*n_act_p);
    m[c] = accum[c] / na;
    __syncthreads();
    float s = b_out[c];
    for (int k = 0; k < HID; ++k) s += m[k] * W_out[k * HID + c];
    out[c] = s;
}

extern "C" void kernel_launch(void* const* d_in, const int* in_sizes, int n_in,
                              void* d_out, int out_size, void* d_ws, size_t ws_size,
                              hipStream_t stream) {
    const int n  = in_sizes[0] / INP;   // 50000
    const int nE = in_sizes[1] / 2;     // 800000
    const float* x    = (const float*)d_in[0];
    const int*   ei   = (const int*)d_in[1];
    const int*   src  = ei;
    const int*   dst  = ei + nE;
    const int*   nact = (const int*)d_in[2];
    const float* W_in = (const float*)d_in[3];
    const float* b_in = (const float*)d_in[4];
    const float* W_l  = (const float*)d_in[5];
    const float* b_l  = (const float*)d_in[6];
    const float* lng  = (const float*)d_in[7];
    const float* lnb  = (const float*)d_in[8];
    const float* W_o  = (const float*)d_in[9];
    const float* b_o  = (const float*)d_in[10];

    char* ws = (char*)d_ws;
    size_t off = 0;
    auto alloc = [&](size_t bytes) {
        void* p = ws + off;
        off = (off + bytes + 255) & ~((size_t)255);
        return p;
    };
    float* h    = (float*)alloc((size_t)n * HID * 4);
    float* agg  = (float*)alloc((size_t)n * HID * 4);
    int*   cnt  = (int*)alloc((size_t)n * 4);
    int*   rowp = (int*)alloc((size_t)(n + 1) * 4);
    int*   curs = (int*)alloc((size_t)n * 4);
    float* invd = (float*)alloc((size_t)n * 4);
    int*   csrc = (int*)alloc((size_t)nE * 4);
    int*   bsum = (int*)alloc(1024);
    float* accum = (float*)alloc(HID * 4);

    hipMemsetAsync(cnt, 0, (size_t)n * 4, stream);
    hipMemsetAsync(accum, 0, HID * 4, stream);

    int egrid = (nE + 255) / 256;
    int nb = (n + 255) / 256;
    k_count<<<egrid, 256, 0, stream>>>(dst, nE, cnt);
    k_scan1<<<nb, 256, 0, stream>>>(cnt, n, rowp, bsum);
    k_scan2<<<1, 256, 0, stream>>>(bsum, nb);
    k_scan3<<<nb, 256, 0, stream>>>(rowp, bsum, cnt, n, nE, curs, invd);
    k_fill<<<egrid, 256, 0, stream>>>(src, dst, nE, curs, csrc);

    int tgrid = (n + RT - 1) / RT;
    k_inproj<<<tgrid, 256, 0, stream>>>(x, W_in, b_in, h, n);
    for (int l = 0; l < 3; ++l) {
        k_agg<<<(n + 3) / 4, 256, 0, stream>>>(h, rowp, csrc, invd, agg, n);
        k_layer<<<tgrid, 256, 0, stream>>>(h, agg, W_l + (size_t)l * HID * HID,
                                           b_l + l * HID, lng + l * HID, lnb + l * HID, n);
    }
    k_rowsum<<<(n + 127) / 128, 128, 0, stream>>>(h, nact, accum, n);
    k_out<<<1, HID, 0, stream>>>(accum, nact, W_o, b_o, (float*)d_out);
}

// Round 3
// 366.345 us; speedup vs baseline: 7.6393x; 1.3920x over previous
//
#include <hip/hip_runtime.h>

#define HID 128
#define INP 64
#define LN_EPS 1e-5f
#define RT 64   // rows per block in GEMM kernels

typedef __attribute__((ext_vector_type(8))) short bf16x8;
typedef __attribute__((ext_vector_type(4))) float f32x4;

__device__ __forceinline__ unsigned f2bf(float f) {
    unsigned u = __float_as_uint(f);
    return (u + 0x7FFFu + ((u >> 16) & 1u)) >> 16;   // RNE
}
__device__ __forceinline__ float bflo(unsigned v) { return __uint_as_float(v << 16); }
__device__ __forceinline__ float bfhi(unsigned v) { return __uint_as_float(v & 0xFFFF0000u); }

// ---------------- CSR build ----------------
__global__ void k_count(const int* __restrict__ dst, int nE, int* __restrict__ cnt) {
    int e = blockIdx.x * blockDim.x + threadIdx.x;
    if (e < nE) atomicAdd(&cnt[dst[e]], 1);
}

__global__ void k_scan1(const int* __restrict__ cnt, int n, int* __restrict__ rowp, int* __restrict__ bsum) {
    __shared__ int s[256];
    int i = blockIdx.x * 256 + threadIdx.x;
    int v = (i < n) ? cnt[i] : 0;
    s[threadIdx.x] = v;
    __syncthreads();
    for (int off = 1; off < 256; off <<= 1) {
        int t = (threadIdx.x >= off) ? s[threadIdx.x - off] : 0;
        __syncthreads();
        s[threadIdx.x] += t;
        __syncthreads();
    }
    if (i < n) rowp[i] = s[threadIdx.x] - v;  // exclusive
    if (threadIdx.x == 255) bsum[blockIdx.x] = s[255];
}

__global__ void k_scan2(int* __restrict__ bsum, int nb) {
    __shared__ int s[256];
    int v = (threadIdx.x < nb) ? bsum[threadIdx.x] : 0;
    s[threadIdx.x] = v;
    __syncthreads();
    for (int off = 1; off < 256; off <<= 1) {
        int t = (threadIdx.x >= off) ? s[threadIdx.x - off] : 0;
        __syncthreads();
        s[threadIdx.x] += t;
        __syncthreads();
    }
    if (threadIdx.x < nb) bsum[threadIdx.x] = s[threadIdx.x] - v;
}

__global__ void k_scan3(int* __restrict__ rowp, const int* __restrict__ bsum, const int* __restrict__ cnt,
                        int n, int nE, int* __restrict__ cursor, float* __restrict__ invd) {
    int i = blockIdx.x * 256 + threadIdx.x;
    if (i < n) {
        int rp = rowp[i] + bsum[blockIdx.x];
        rowp[i] = rp;
        cursor[i] = rp;
        int c = cnt[i];
        invd[i] = 1.0f / (float)(c > 1 ? c : 1);
    } else if (i == n) {
        rowp[n] = nE;
    }
}

__global__ void k_fill(const int* __restrict__ src, const int* __restrict__ dst, int nE,
                       int* __restrict__ cursor, int* __restrict__ csrc) {
    int e = blockIdx.x * blockDim.x + threadIdx.x;
    if (e < nE) {
        int p = atomicAdd(&cursor[dst[e]], 1);
        csrc[p] = src[e];
    }
}

// ---------------- weight prep: transpose + bf16 convert ----------------
// Wt_in[col][k] (128x64), Wt_l[l][col][k] (3 x 128x128)
__global__ void w_prep(const float* __restrict__ W_in, const float* __restrict__ W_l,
                       unsigned short* __restrict__ Wt_in, unsigned short* __restrict__ Wt_l) {
    int i = blockIdx.x * 256 + threadIdx.x;
    if (i < 128 * 64) {
        int col = i >> 6, k = i & 63;
        Wt_in[i] = (unsigned short)f2bf(W_in[(size_t)k * HID + col]);
    }
    int j = i - 128 * 64;
    if (j >= 0 && j < 3 * 128 * 128) {
        int l = j >> 14, r = j & 16383;
        int col = r >> 7, k = r & 127;
        Wt_l[j] = (unsigned short)f2bf(W_l[(size_t)l * 16384 + (size_t)k * HID + col]);
    }
}

// ---------------- aggregation: aggb[v] = bf16( (sum_{u in N(v)} hb[u]) * invd[v] ) ----------------
// one wave per node, 2 bf16 (one uint) per lane, 4-edge unroll
__global__ __launch_bounds__(256) void k_agg(const unsigned* __restrict__ hb, const int* __restrict__ rowp,
                                             const int* __restrict__ csrc, const float* __restrict__ invd,
                                             unsigned* __restrict__ aggb, int n) {
    int node = blockIdx.x * 4 + (threadIdx.x >> 6);
    if (node >= n) return;
    int lane = threadIdx.x & 63;
    int e0 = rowp[node], e1 = rowp[node + 1];
    float ax = 0.f, ay = 0.f;
    int e = e0;
    for (; e + 4 <= e1; e += 4) {
        int s0 = csrc[e], s1 = csrc[e + 1], s2 = csrc[e + 2], s3 = csrc[e + 3];
        unsigned v0 = hb[(size_t)s0 * 64 + lane];
        unsigned v1 = hb[(size_t)s1 * 64 + lane];
        unsigned v2 = hb[(size_t)s2 * 64 + lane];
        unsigned v3 = hb[(size_t)s3 * 64 + lane];
        ax += (bflo(v0) + bflo(v1)) + (bflo(v2) + bflo(v3));
        ay += (bfhi(v0) + bfhi(v1)) + (bfhi(v2) + bfhi(v3));
    }
    for (; e < e1; ++e) {
        unsigned v0 = hb[(size_t)csrc[e] * 64 + lane];
        ax += bflo(v0);
        ay += bfhi(v0);
    }
    float inv = invd[node];
    aggb[(size_t)node * 64 + lane] = f2bf(ax * inv) | (f2bf(ay * inv) << 16);
}

// ---------------- in-projection (MFMA): h = x @ W_in + b_in ; also writes hb ----------------
__global__ __launch_bounds__(256) void k_inproj(const float* __restrict__ x,
                                                const unsigned short* __restrict__ Wt,  // [128][64] bf16
                                                const float* __restrict__ b,
                                                float* __restrict__ h, unsigned short* __restrict__ hb, int n) {
    __shared__ unsigned short xs[RT * INP];  // 8 KB, swizzled
    const int tid = threadIdx.x;
    const int row0 = blockIdx.x * RT;

    // stage x -> bf16: 64x64 = 512 chunks of 8; 2 per thread
#pragma unroll
    for (int j = 0; j < 2; ++j) {
        int fid = tid + j * 256;
        int r = fid >> 3, c = fid & 7;
        int grow = row0 + r;
        unsigned o[4] = {0, 0, 0, 0};
        if (grow < n) {
            float4 v0 = *reinterpret_cast<const float4*>(x + (size_t)grow * INP + c * 8);
            float4 v1 = *reinterpret_cast<const float4*>(x + (size_t)grow * INP + c * 8 + 4);
            o[0] = f2bf(v0.x) | (f2bf(v0.y) << 16);
            o[1] = f2bf(v0.z) | (f2bf(v0.w) << 16);
            o[2] = f2bf(v1.x) | (f2bf(v1.y) << 16);
            o[3] = f2bf(v1.z) | (f2bf(v1.w) << 16);
        }
        int sw = c ^ (r & 7);
        *reinterpret_cast<uint4*>(xs + r * INP + sw * 8) = make_uint4(o[0], o[1], o[2], o[3]);
    }
    __syncthreads();

    const int l = tid & 63;
    const int w = tid >> 6;
    const int l15 = l & 15, lg = l >> 4;
    const int xrow = w * 16 + l15;

    f32x4 acc[8];
#pragma unroll
    for (int t = 0; t < 8; ++t) acc[t] = (f32x4){0.f, 0.f, 0.f, 0.f};

#pragma unroll
    for (int kc = 0; kc < 2; ++kc) {
        int bc = (kc * 4 + lg) ^ (xrow & 7);
        bf16x8 bfrag = *reinterpret_cast<const bf16x8*>(xs + xrow * INP + bc * 8);
        const unsigned short* wp = Wt + (size_t)l15 * INP + kc * 32 + lg * 8;
        bf16x8 af[8];
#pragma unroll
        for (int t = 0; t < 8; ++t) af[t] = *reinterpret_cast<const bf16x8*>(wp + (size_t)t * 16 * INP);
#pragma unroll
        for (int t = 0; t < 8; ++t)
            acc[t] = __builtin_amdgcn_mfma_f32_16x16x32_bf16(af[t], bfrag, acc[t], 0, 0, 0);
    }

    int grow = row0 + xrow;
    if (grow < n) {
#pragma unroll
        for (int t = 0; t < 8; ++t) {
            int c0 = t * 16 + lg * 4;
            f32x4 bb = *reinterpret_cast<const f32x4*>(b + c0);
            f32x4 o = acc[t] + bb;
            *reinterpret_cast<f32x4*>(h + (size_t)grow * HID + c0) = o;
            uint2 p;
            p.x = f2bf(o.x) | (f2bf(o.y) << 16);
            p.y = f2bf(o.z) | (f2bf(o.w) << 16);
            *reinterpret_cast<uint2*>(hb + (size_t)grow * HID + c0) = p;
        }
    }
}

// ---------------- fused layer (MFMA): h = relu(LN((h+agg)@W + b)*g + lnb) + h ----------------
__global__ __launch_bounds__(256) void k_layer(float* __restrict__ h, unsigned short* __restrict__ hb,
                                               const unsigned short* __restrict__ aggb,
                                               const unsigned short* __restrict__ Wt,  // [128][128] bf16
                                               const float* __restrict__ bias, const float* __restrict__ g,
                                               const float* __restrict__ lnb, int n) {
    __shared__ unsigned short xs[RT * HID];  // 16 KB, swizzled
    const int tid = threadIdx.x;
    const int row0 = blockIdx.x * RT;

    // stage X = hb + aggb (bf16): 64x128 = 1024 chunks of 8; 4 per thread
#pragma unroll
    for (int j = 0; j < 4; ++j) {
        int fid = tid + j * 256;
        int r = fid >> 4, c = fid & 15;
        int grow = row0 + r;
        unsigned o[4] = {0, 0, 0, 0};
        if (grow < n) {
            uint4 hv = *reinterpret_cast<const uint4*>(hb + (size_t)grow * HID + c * 8);
            uint4 av = *reinterpret_cast<const uint4*>(aggb + (size_t)grow * HID + c * 8);
            unsigned hvv[4] = {hv.x, hv.y, hv.z, hv.w};
            unsigned avv[4] = {av.x, av.y, av.z, av.w};
#pragma unroll
            for (int q = 0; q < 4; ++q) {
                float lo = bflo(hvv[q]) + bflo(avv[q]);
                float hi = bfhi(hvv[q]) + bfhi(avv[q]);
                o[q] = f2bf(lo) | (f2bf(hi) << 16);
            }
        }
        int sw = c ^ (r & 7);
        *reinterpret_cast<uint4*>(xs + r * HID + sw * 8) = make_uint4(o[0], o[1], o[2], o[3]);
    }
    __syncthreads();

    const int l = tid & 63;
    const int w = tid >> 6;
    const int l15 = l & 15, lg = l >> 4;
    const int xrow = w * 16 + l15;

    f32x4 acc[8];
#pragma unroll
    for (int t = 0; t < 8; ++t) acc[t] = (f32x4){0.f, 0.f, 0.f, 0.f};

#pragma unroll
    for (int kc = 0; kc < 4; ++kc) {
        int bc = (kc * 4 + lg) ^ (xrow & 7);
        bf16x8 bfrag = *reinterpret_cast<const bf16x8*>(xs + xrow * HID + bc * 8);
        const unsigned short* wp = Wt + (size_t)l15 * HID + kc * 32 + lg * 8;
        bf16x8 af[8];
#pragma unroll
        for (int t = 0; t < 8; ++t) af[t] = *reinterpret_cast<const bf16x8*>(wp + (size_t)t * 16 * HID);
#pragma unroll
        for (int t = 0; t < 8; ++t)
            acc[t] = __builtin_amdgcn_mfma_f32_16x16x32_bf16(af[t], bfrag, acc[t], 0, 0, 0);
    }

    // add bias, compute LN stats (row = xrow; this lane holds cols t*16+lg*4+{0..3})
    float s = 0.f, q = 0.f;
#pragma unroll
    for (int t = 0; t < 8; ++t) {
        int c0 = t * 16 + lg * 4;
        f32x4 bb = *reinterpret_cast<const f32x4*>(bias + c0);
        acc[t] = acc[t] + bb;
        s += acc[t].x + acc[t].y + acc[t].z + acc[t].w;
        q += acc[t].x * acc[t].x + acc[t].y * acc[t].y + acc[t].z * acc[t].z + acc[t].w * acc[t].w;
    }
    s += __shfl_xor(s, 16, 64);
    s += __shfl_xor(s, 32, 64);
    q += __shfl_xor(q, 16, 64);
    q += __shfl_xor(q, 32, 64);
    float mu = s * (1.0f / HID);
    float var = q * (1.0f / HID) - mu * mu;
    float rs = rsqrtf(var + LN_EPS);

    int grow = row0 + xrow;
    if (grow < n) {
#pragma unroll
        for (int t = 0; t < 8; ++t) {
            int c0 = t * 16 + lg * 4;
            f32x4 res = *reinterpret_cast<const f32x4*>(h + (size_t)grow * HID + c0);
            f32x4 gv = *reinterpret_cast<const f32x4*>(g + c0);
            f32x4 lb = *reinterpret_cast<const f32x4*>(lnb + c0);
            f32x4 o;
            o.x = fmaxf((acc[t].x - mu) * rs * gv.x + lb.x, 0.f) + res.x;
            o.y = fmaxf((acc[t].y - mu) * rs * gv.y + lb.y, 0.f) + res.y;
            o.z = fmaxf((acc[t].z - mu) * rs * gv.z + lb.z, 0.f) + res.z;
            o.w = fmaxf((acc[t].w - mu) * rs * gv.w + lb.w, 0.f) + res.w;
            *reinterpret_cast<f32x4*>(h + (size_t)grow * HID + c0) = o;
            uint2 p;
            p.x = f2bf(o.x) | (f2bf(o.y) << 16);
            p.y = f2bf(o.z) | (f2bf(o.w) << 16);
            *reinterpret_cast<uint2*>(hb + (size_t)grow * HID + c0) = p;
        }
    }
}

// ---------------- final: accum[c] = sum over rows < n_act of h[r][c] ----------------
__global__ void k_rowsum(const float* __restrict__ h, const int* __restrict__ n_act_p,
                         float* __restrict__ accum, int n) {
    int na = *n_act_p;
    int row0 = blockIdx.x * 128;
    int c = threadIdx.x;
    int rend = row0 + 128;
    if (rend > na) rend = na;
    float s = 0.f;
    for (int r = row0; r < rend; ++r) s += h[(size_t)r * HID + c];
    if (row0 < na) atomicAdd(&accum[c], s);
}

__global__ void k_out(const float* __restrict__ accum, const int* __restrict__ n_act_p,
                      const float* __restrict__ W_out, const float* __restrict__ b_out,
                      float* __restrict__ out) {
    __shared__ float m[HID];
    int c = threadIdx.x;
    float na = (float)(*n_act_p);
    m[c] = accum[c] / na;
    __syncthreads();
    float s = b_out[c];
    for (int k = 0; k < HID; ++k) s += m[k] * W_out[k * HID + c];
    out[c] = s;
}

extern "C" void kernel_launch(void* const* d_in, const int* in_sizes, int n_in,
                              void* d_out, int out_size, void* d_ws, size_t ws_size,
                              hipStream_t stream) {
    const int n  = in_sizes[0] / INP;   // 50000
    const int nE = in_sizes[1] / 2;     // 800000
    const float* x    = (const float*)d_in[0];
    const int*   ei   = (const int*)d_in[1];
    const int*   src  = ei;
    const int*   dst  = ei + nE;
    const int*   nact = (const int*)d_in[2];
    const float* W_in = (const float*)d_in[3];
    const float* b_in = (const float*)d_in[4];
    const float* W_l  = (const float*)d_in[5];
    const float* b_l  = (const float*)d_in[6];
    const float* lng  = (const float*)d_in[7];
    const float* lnb  = (const float*)d_in[8];
    const float* W_o  = (const float*)d_in[9];
    const float* b_o  = (const float*)d_in[10];

    char* ws = (char*)d_ws;
    size_t off = 0;
    auto alloc = [&](size_t bytes) {
        void* p = ws + off;
        off = (off + bytes + 255) & ~((size_t)255);
        return p;
    };
    float*          h     = (float*)alloc((size_t)n * HID * 4);
    unsigned short* hb    = (unsigned short*)alloc((size_t)n * HID * 2);
    unsigned short* aggb  = (unsigned short*)alloc((size_t)n * HID * 2);
    int*   cnt  = (int*)alloc((size_t)n * 4);
    int*   rowp = (int*)alloc((size_t)(n + 1) * 4);
    int*   curs = (int*)alloc((size_t)n * 4);
    float* invd = (float*)alloc((size_t)n * 4);
    int*   csrc = (int*)alloc((size_t)nE * 4);
    int*   bsum = (int*)alloc(1024);
    float* accum = (float*)alloc(HID * 4);
    unsigned short* Wt_in = (unsigned short*)alloc(128 * 64 * 2);
    unsigned short* Wt_l  = (unsigned short*)alloc(3 * 128 * 128 * 2);

    hipMemsetAsync(cnt, 0, (size_t)n * 4, stream);
    hipMemsetAsync(accum, 0, HID * 4, stream);

    int egrid = (nE + 255) / 256;
    int nb = (n + 255) / 256;
    w_prep<<<(128 * 64 + 3 * 128 * 128 + 255) / 256, 256, 0, stream>>>(W_in, W_l, Wt_in, Wt_l);
    k_count<<<egrid, 256, 0, stream>>>(dst, nE, cnt);
    k_scan1<<<nb, 256, 0, stream>>>(cnt, n, rowp, bsum);
    k_scan2<<<1, 256, 0, stream>>>(bsum, nb);
    k_scan3<<<nb, 256, 0, stream>>>(rowp, bsum, cnt, n, nE, curs, invd);
    k_fill<<<egrid, 256, 0, stream>>>(src, dst, nE, curs, csrc);

    int tgrid = (n + RT - 1) / RT;
    k_inproj<<<tgrid, 256, 0, stream>>>(x, Wt_in, b_in, h, hb, n);
    for (int l = 0; l < 3; ++l) {
        k_agg<<<(n + 3) / 4, 256, 0, stream>>>((const unsigned*)hb, rowp, csrc, invd, (unsigned*)aggb, n);
        k_layer<<<tgrid, 256, 0, stream>>>(h, hb, aggb, Wt_l + (size_t)l * 128 * 128,
                                           b_l + l * HID, lng + l * HID, lnb + l * HID, n);
    }
    k_rowsum<<<(n + 127) / 128, 128, 0, stream>>>(h, nact, accum, n);
    k_out<<<1, HID, 0, stream>>>(accum, nact, W_o, b_o, (float*)d_out);
}